// Round 2
// baseline (1763.653 us; speedup 1.0000x reference)
//
#include <hip/hip_runtime.h>

// CostVolume: B=4,H=256,W=512,C=64,D=64.
// out[b,h,w,d] = (w-d-1>=0) ? (1/64) * sum_c L[b,h,w,c]*R[b,h,w-d-1,c] : 0
//
// R5: register-blocked banded GEMM on top of LDS tiles.
// R4 post-mortem: LDS-read-bound (9.44M ds_read_b128, ~10cyc each incl 18.35M
// conflict cycles ~= the whole 137us dispatch; VALUBusy 33%, HBM 27%).
// Changes:
//  (1) Per-thread 4w x 8d register tile: banded structure needs only
//      4 L + 11 R quads per k-chunk for 32 f4-FMAs (0.47 reads/FMA, was 1.125)
//      -> 3.93M reads. Lane map (ta,tb)=8x8: R row = 4ta-8tb+c has only 22
//      distinct values/wave -> broadcast dedup, ~3-4 cyc/read.
//  (2) k-major LDS planes with row-swizzle swz(r)=(r&~7)|((r^(r>>3))&7):
//      swizzle lives entirely in the row term, so compute reads keep
//      base + k*stride immediate offsets; consecutive rows -> distinct bank
//      slots. Staging at 32B/thread (8 threads/row) -> writes spread over 8
//      rows = 8 slots, conflict-free, globally coalesced (2KB/wave).
// Budget: LDS ~20-25us, VALU ~27us, HBM ~45-55us -> HBM-bound.

#define WW 512
#define CC 64
#define DD 64
#define WT 128     // w-tile per block
#define NRR 192    // staged R rows: [w0-64, w0+128)
#define NLL 128    // staged L rows: [w0, w0+128)

typedef float f4 __attribute__((ext_vector_type(4)));

__device__ __forceinline__ int swz(int r) {
    return (r & ~7) | ((r ^ (r >> 3)) & 7);
}

__global__ __launch_bounds__(256, 2)
void CostVolume_47433618817551_kernel(const float* __restrict__ left,
                                      const float* __restrict__ right,
                                      float* __restrict__ out) {
    __shared__ f4 sR[16 * NRR];   // 48 KB, k-major planes
    __shared__ f4 sL[16 * NLL];   // 32 KB

    const int tid = threadIdx.x;
    const int bid = blockIdx.x;
    const int bh  = bid >> 2;            // 0..1023
    const int w0  = (bid & 3) * WT;      // 0,128,256,384

    const float* Lg = left  + (size_t)bh * (WW * CC);
    const float* Rg = right + (size_t)bh * (WW * CC);
    float*       Og = out   + (size_t)bh * (WW * DD);

    // ---- stage R rows [w0-64, w0+128): 32B per thread, 8 threads/row.
    // Global: per wave 8 full rows = 2KB contiguous. LDS: 8 rows -> 8 distinct
    // swizzled bank slots -> conflict-free writes.
#pragma unroll
    for (int it = 0; it < 6; ++it) {
        const int idx = tid + it * 256;   // 0..1535
        const int row = idx >> 3;         // 0..191
        const int kp  = idx & 7;          // 32B chunk within row
        int grow = row + w0 - 64;
        grow = grow < 0 ? 0 : grow;       // clamp; masked at store
        const f4* gp = (const f4*)(Rg + (size_t)grow * CC + kp * 8);
        const f4 a = gp[0], b = gp[1];
        const int c = swz(row);
        sR[(2 * kp) * NRR + c]     = a;
        sR[(2 * kp + 1) * NRR + c] = b;
    }
    // ---- stage L rows [w0, w0+128)
#pragma unroll
    for (int it = 0; it < 4; ++it) {
        const int idx = tid + it * 256;   // 0..1023
        const int row = idx >> 3;         // 0..127
        const int kp  = idx & 7;
        const f4* gp = (const f4*)(Lg + (size_t)(w0 + row) * CC + kp * 8);
        const f4 a = gp[0], b = gp[1];
        const int c = swz(row);
        sL[(2 * kp) * NLL + c]     = a;
        sL[(2 * kp + 1) * NLL + c] = b;
    }
    __syncthreads();

    const int wv   = tid >> 6;     // wave 0..3 -> w-range [wv*32, wv*32+32)
    const int lane = tid & 63;
    const int ta   = lane >> 3;    // 0..7: w sub-tile (4 w each)
    const int tb   = lane & 7;     // 0..7: d sub-tile (8 d each)
    const int wlb  = wv * 32 + ta * 4;   // local w base, 0..124
    const int db   = tb * 8;             // d base
    // R tile row for (i,j): ur = 63 + wlb - db + (i-j) = ur0 + o, o=i-j+7 in [0,10]
    const int ur0  = 56 + wlb - db;      // 0..180

    const f4* rb[11];
#pragma unroll
    for (int o = 0; o < 11; ++o) rb[o] = &sR[swz(ur0 + o)];
    const f4* lb[4];
#pragma unroll
    for (int i = 0; i < 4; ++i) lb[i] = &sL[swz(wlb + i)];

    f4 acc[4][8];
#pragma unroll
    for (int i = 0; i < 4; ++i)
#pragma unroll
        for (int j = 0; j < 8; ++j) acc[i][j] = (f4){0.f, 0.f, 0.f, 0.f};

#pragma unroll
    for (int k = 0; k < 16; ++k) {
        f4 rf[11], lf[4];
#pragma unroll
        for (int o = 0; o < 11; ++o) rf[o] = rb[o][k * NRR];   // base + k*3072B
#pragma unroll
        for (int i = 0; i < 4; ++i) lf[i] = lb[i][k * NLL];    // base + k*2048B
#pragma unroll
        for (int i = 0; i < 4; ++i)
#pragma unroll
            for (int j = 0; j < 8; ++j)
                acc[i][j] += lf[i] * rf[i - j + 7];
    }

#pragma unroll
    for (int i = 0; i < 4; ++i) {
        const int w = w0 + wlb + i;
        float s[8];
#pragma unroll
        for (int j = 0; j < 8; ++j) {
            const f4 a = acc[i][j];
            s[j] = ((a.x + a.y) + (a.z + a.w)) * 0.015625f;
        }
        if (w0 == 0) {   // only first w-tile can have d >= w (clamped R rows)
#pragma unroll
            for (int j = 0; j < 8; ++j)
                if (db + j >= w) s[j] = 0.f;
        }
        const f4 o0 = {s[0], s[1], s[2], s[3]};
        const f4 o1 = {s[4], s[5], s[6], s[7]};
        float* op = Og + (size_t)w * DD + db;
        *(f4*)op       = o0;
        *(f4*)(op + 4) = o1;
    }
}

extern "C" void kernel_launch(void* const* d_in, const int* in_sizes, int n_in,
                              void* d_out, int out_size, void* d_ws, size_t ws_size,
                              hipStream_t stream) {
    const float* left  = (const float*)d_in[0];
    const float* right = (const float*)d_in[1];
    float* o = (float*)d_out;

    // 1024 bh * 4 w-tiles; 256 threads; 80KB LDS -> 2 blocks/CU, 8 waves/CU.
    CostVolume_47433618817551_kernel<<<dim3(4096), dim3(256), 0, stream>>>(
        left, right, o);
}

// Round 3
// 998.871 us; speedup vs baseline: 1.7656x; 1.7656x over previous
//
#include <hip/hip_runtime.h>

// CostVolume: B=4,H=256,W=512,C=64,D=64.
// out[b,h,w,d] = (w-d-1>=0) ? (1/64) * sum_c L[b,h,w,c]*R[b,h,w-d-1,c] : 0
//
// R6: register-blocked (2w x 8d) banded GEMM from swizzled LDS tiles.
// R5 post-mortem: pointer arrays + 4wx8d tile -> scratch spill (FETCH 2.65GB,
// WRITE 2.3GB, VALUBusy 2.4%). Fix: 2wx8d (acc=64 VGPR), integer byte-offset
// addressing (no pointer arrays), everything fully unrolled.
// R4 post-mortem: 18.35M LDS conflict cycles, dominated by 16-way staging
// writes (k-plane stride 768B = 0 mod 32 banks).
// Layout: cell(k,row) = k*NP + ((row&~7) | ((row^(row>>3)^k)&7)).
//  - staging writes: 8 rows x 8 k-pairs/wave -> one 16B access per 4-bank
//    group per cycle = 8-cyc floor (conflict-free).
//  - compute reads: addr = (m ^ ((k&7)<<4)) + k*planeBytes imm; the row>>3
//    XOR rotates the stride-8 row classes across all 8 bank groups; 2x
//    broadcast dedup -> ~4 cyc/wave-read.
// Reads/FMA: (2L + 9R) / 16 f4-FMA = 0.69 (R4: 1.125) -> 5.77M ds_read_b128.
// Budget: LDS ~40us, VALU ~31us, mem ~40us (inputs L3-resident) -> ~75us.

#define WW 512
#define CC 64
#define DD 64
#define WT 128     // w-tile per block
#define NRR 192    // staged R rows: [w0-64, w0+128)
#define NLL 128    // staged L rows: [w0, w0+128)

typedef float f4 __attribute__((ext_vector_type(4)));

__device__ __forceinline__ int swzcell(int row, int k, int np) {
    return k * np + ((row & ~7) | ((row ^ (row >> 3) ^ k) & 7));
}

__global__ __launch_bounds__(256, 2)
void CostVolume_47433618817551_kernel(const float* __restrict__ left,
                                      const float* __restrict__ right,
                                      float* __restrict__ out) {
    __shared__ f4 sR[16 * NRR];   // 48 KB
    __shared__ f4 sL[16 * NLL];   // 32 KB

    const int tid = threadIdx.x;
    const int bid = blockIdx.x;
    const int bh  = bid >> 2;            // 0..1023
    const int w0  = (bid & 3) * WT;      // 0,128,256,384

    const float* Lg = left  + (size_t)bh * (WW * CC);
    const float* Rg = right + (size_t)bh * (WW * CC);
    float*       Og = out   + (size_t)bh * (WW * DD);

    // ---- stage R rows [w0-64, w0+128): 32B/thread, 8 threads per 256B row.
#pragma unroll
    for (int it = 0; it < 6; ++it) {
        const int idx = tid + it * 256;   // 0..1535
        const int row = idx >> 3;         // 0..191
        const int kp  = idx & 7;          // which 32B chunk of the row
        int grow = row + w0 - 64;
        grow = grow < 0 ? 0 : grow;       // clamp; outputs masked at store
        const f4* gp = (const f4*)(Rg + (size_t)grow * CC + kp * 8);
        const f4 a = gp[0], b = gp[1];
        sR[swzcell(row, 2 * kp,     NRR)] = a;
        sR[swzcell(row, 2 * kp + 1, NRR)] = b;
    }
    // ---- stage L rows [w0, w0+128)
#pragma unroll
    for (int it = 0; it < 4; ++it) {
        const int idx = tid + it * 256;   // 0..1023
        const int row = idx >> 3;         // 0..127
        const int kp  = idx & 7;
        const f4* gp = (const f4*)(Lg + (size_t)(w0 + row) * CC + kp * 8);
        const f4 a = gp[0], b = gp[1];
        sL[swzcell(row, 2 * kp,     NLL)] = a;
        sL[swzcell(row, 2 * kp + 1, NLL)] = b;
    }
    __syncthreads();

    const int wv   = tid >> 6;     // wave 0..3
    const int lane = tid & 63;
    const int ta   = lane >> 3;    // 0..7: w pairs (stride 2)
    const int tb   = lane & 7;     // 0..7: d octets
    const int db   = tb * 8;

    const char* sRb = (const char*)sR;
    const char* sLb = (const char*)sL;

#pragma unroll 1
    for (int pass = 0; pass < 2; ++pass) {
        const int wlb = pass * 64 + wv * 16 + ta * 2;  // local w base, 0..126
        // R tile row for (i,j): u = 63 + wlb - db + (i-j) = u0 + o, o=i-j+7
        const int u0  = 56 + wlb - db;                 // 0..182

        // Plane-0 byte offsets; bits 4-6 hold the XOR-able swizzle slot.
        int mR[9];
#pragma unroll
        for (int o = 0; o < 9; ++o) {
            const int u = u0 + o;
            mR[o] = ((u & ~7) | ((u ^ (u >> 3)) & 7)) << 4;
        }
        int mL[2];
#pragma unroll
        for (int i = 0; i < 2; ++i) {
            const int r = wlb + i;
            mL[i] = ((r & ~7) | ((r ^ (r >> 3)) & 7)) << 4;
        }

        f4 acc[2][8];
#pragma unroll
        for (int i = 0; i < 2; ++i)
#pragma unroll
            for (int j = 0; j < 8; ++j) acc[i][j] = (f4){0.f, 0.f, 0.f, 0.f};

#pragma unroll
        for (int k = 0; k < 16; ++k) {
            const int kx = (k & 7) << 4;
            const f4 lf0 = *(const f4*)(sLb + (mL[0] ^ kx) + k * (NLL * 16));
            const f4 lf1 = *(const f4*)(sLb + (mL[1] ^ kx) + k * (NLL * 16));
            f4 rf[9];
#pragma unroll
            for (int o = 0; o < 9; ++o)
                rf[o] = *(const f4*)(sRb + (mR[o] ^ kx) + k * (NRR * 16));
#pragma unroll
            for (int j = 0; j < 8; ++j) {
                acc[0][j] += lf0 * rf[7 - j];   // i=0: o = 7-j
                acc[1][j] += lf1 * rf[8 - j];   // i=1: o = 8-j
            }
        }

#pragma unroll
        for (int i = 0; i < 2; ++i) {
            const int w = w0 + wlb + i;
            float s[8];
#pragma unroll
            for (int j = 0; j < 8; ++j) {
                const f4 a = acc[i][j];
                s[j] = ((a.x + a.y) + (a.z + a.w)) * 0.015625f;
            }
            if (w0 == 0) {   // only first w-tile can have d >= w
#pragma unroll
                for (int j = 0; j < 8; ++j)
                    if (db + j >= w) s[j] = 0.f;
            }
            const f4 o0 = {s[0], s[1], s[2], s[3]};
            const f4 o1 = {s[4], s[5], s[6], s[7]};
            float* op = Og + (size_t)w * DD + db;
            *(f4*)op       = o0;
            *(f4*)(op + 4) = o1;
        }
    }
}

extern "C" void kernel_launch(void* const* d_in, const int* in_sizes, int n_in,
                              void* d_out, int out_size, void* d_ws, size_t ws_size,
                              hipStream_t stream) {
    const float* left  = (const float*)d_in[0];
    const float* right = (const float*)d_in[1];
    float* o = (float*)d_out;

    // 1024 bh * 4 w-tiles; 256 threads; 80KB LDS -> 2 blocks/CU, 8 waves/CU.
    CostVolume_47433618817551_kernel<<<dim3(4096), dim3(256), 0, stream>>>(
        left, right, o);
}